// Round 6
// baseline (490.852 us; speedup 1.0000x reference)
//
#include <hip/hip_runtime.h>
#include <math.h>

#define B   4
#define C   128
#define N   2048
#define K   16
#define G   4
#define LCH 96
#define NLCH 32
#define CLG 24   // LCH/G
#define CNG 8    // NLCH/G
#define CH  64   // C/2 (abs_x channels)

// ---------------------------------------------------------------------------
// Kernel 1: local path. One block = 4 consecutive n positions.
// Wave layout: lane = nsub(2b) x kk(4b). Wave g (0..3) owns channel group g:
// computes q,k,v rows [g*24, g*24+24) for its 4 n with accumulators in
// registers, score/softmax in-lane, atomic scatter into global score
// (collision-free per (b,n) since idx comes from argsort -> scatter-add
// == reference .set + sum), and out_l via an in-wave 16-lane shfl
// reduction (no LDS round-trip, no bank conflicts). W reads are
// wave-uniform -> scalar loads; c-loop unrolled x4 so consecutive-c
// weights can merge into s_load_dwordx4.
// ---------------------------------------------------------------------------
__global__ __launch_bounds__(256) void k_local(
    const float* __restrict__ x, const int* __restrict__ idx,
    const float* __restrict__ Wq, const float* __restrict__ Wk,
    const float* __restrict__ Wv,
    float* __restrict__ out, float* __restrict__ score)
{
    __shared__ float xs[C * 64];     // [c][nsub*16+kk]  32 KB -> ~4 blocks/CU

    const int blk = blockIdx.x;          // b*(N/4) + n0/4
    const int b  = blk >> 9;
    const int n0 = (blk & 511) << 2;
    const int tid  = threadIdx.x;
    const int lane = tid & 63;
    const int g = __builtin_amdgcn_readfirstlane(tid >> 6);

    // ---- stage x[b,:,n0:n0+4,:] : 8192 floats = 2048 float4, coalesced ----
    {
        const float4* xg  = reinterpret_cast<const float4*>(x);
        float4*       xsv = reinterpret_cast<float4*>(xs);
        for (int i = tid; i < C * 16; i += 256) {
            const int c = i >> 4, j = i & 15;
            xsv[i] = xg[((size_t)(b * C + c) * N + n0) * 4 + j];
        }
    }
    __syncthreads();

    // ---- projection: 24 q + 24 k + 24 v rows per wave, accs in registers ----
    float accq[CLG], acck[CLG], accv[CLG];
#pragma unroll
    for (int i = 0; i < CLG; i++) { accq[i] = 0.f; acck[i] = 0.f; accv[i] = 0.f; }
    const float* wq = Wq + (size_t)g * CLG * C;
    const float* wk = Wk + (size_t)g * CLG * C;
    const float* wv = Wv + (size_t)g * CLG * C;
#pragma unroll 4
    for (int c = 0; c < C; c++) {
        const float xv = xs[c * 64 + lane];
#pragma unroll
        for (int i = 0; i < CLG; i++) {
            accq[i] = fmaf(wq[i * C + c], xv, accq[i]);
            acck[i] = fmaf(wk[i * C + c], xv, acck[i]);
            accv[i] = fmaf(wv[i * C + c], xv, accv[i]);
        }
    }

    // ---- score (in-lane over 24 channels) + softmax over kk (16-lane grp) ----
    float s = 0.f;
#pragma unroll
    for (int i = 0; i < CLG; i++) s = fmaf(accq[i], acck[i], s);
    float m = s;
#pragma unroll
    for (int w = 1; w < 16; w <<= 1) m = fmaxf(m, __shfl_xor(m, w));
    const float e = expf(s - m);
    float sum = e;
#pragma unroll
    for (int w = 1; w < 16; w <<= 1) sum += __shfl_xor(sum, w);
    const float ow = e / sum;

    // ---- atomic scatter into score[b,g,idx] ----
    {
        const int nsub = lane >> 4, kk = lane & 15;
        const int m_idx = idx[((size_t)b * N + n0 + nsub) * K + kk];
        atomicAdd(&score[(b * G + g) * N + m_idx], ow);
    }

    // ---- out_l[b, g*24+i, n0+ns] = sum over the 16 kk-lanes of ow*v ----
    {
        const int nsub = lane >> 4, kk = lane & 15;
#pragma unroll
        for (int i = 0; i < CLG; i++) {
            float t = ow * accv[i];
#pragma unroll
            for (int w = 1; w < 16; w <<= 1) t += __shfl_xor(t, w);
            if (kk == 0) {
                const int o = g * CLG + i;
                out[((size_t)b * C + o) * N + n0 + nsub] = t;
            }
        }
    }
}

// ---------------------------------------------------------------------------
// Kernel 2: per (b,g) top-16 of score with lower-index tie-break (wave
// shfl reduction; tie-break = value desc, index asc at thread, lane and
// wave level -> matches jax.lax.top_k), then gather+project kn_g / vn_g,
// vn_g *= tanh(val).
// ---------------------------------------------------------------------------
__global__ __launch_bounds__(256) void k_topk(
    const float* __restrict__ abs_x, const float* __restrict__ score,
    const float* __restrict__ Wnk, const float* __restrict__ Wnv,
    float* __restrict__ kng, float* __restrict__ vng)
{
    __shared__ float s[N];
    __shared__ float rv[4];
    __shared__ int   ri[4];
    __shared__ int   selS[K];
    __shared__ float valS[K];

    const int bg = blockIdx.x;
    const int b = bg >> 2, g = bg & 3;
    const int tid = threadIdx.x;
    const int lane = tid & 63, w = tid >> 6;

    for (int i = tid; i < N; i += 256) s[i] = score[bg * N + i];
    __syncthreads();

    for (int t = 0; t < K; t++) {
        float bv = -INFINITY; int bi = N;
        for (int i = tid; i < N; i += 256) {
            const float v = s[i];
            if (v > bv) { bv = v; bi = i; }   // ascending stride: first-seen = lowest idx
        }
#pragma unroll
        for (int mask = 1; mask < 64; mask <<= 1) {
            const float ov = __shfl_xor(bv, mask);
            const int   oi = __shfl_xor(bi, mask);
            if (ov > bv || (ov == bv && oi < bi)) { bv = ov; bi = oi; }
        }
        if (lane == 0) { rv[w] = bv; ri[w] = bi; }
        __syncthreads();
        if (tid == 0) {
            float fv = rv[0]; int fi = ri[0];
            for (int j = 1; j < 4; j++)
                if (rv[j] > fv || (rv[j] == fv && ri[j] < fi)) { fv = rv[j]; fi = ri[j]; }
            selS[t] = fi; valS[t] = fv; s[fi] = -INFINITY;
        }
        __syncthreads();
    }

    // kn_g, vn_g: 8 channels x 16 selected positions, 64-length dots
    if (tid < CNG * K) {
        const int c = tid >> 4, kk = tid & 15;
        const int sel = selS[kk];
        const float* wkrow = Wnk + (g * CNG + c) * CH;
        const float* wvrow = Wnv + (g * CNG + c) * CH;
        float ka = 0.f, va = 0.f;
        for (int cc = 0; cc < CH; cc++) {
            const float ax = abs_x[((size_t)b * CH + cc) * N + sel];
            ka = fmaf(wkrow[cc], ax, ka);
            va = fmaf(wvrow[cc], ax, va);
        }
        va *= tanhf(valS[kk]);
        kng[bg * CNG * K + c * K + kk] = ka;
        vng[bg * CNG * K + c * K + kk] = va;
    }
}

// ---------------------------------------------------------------------------
// Kernel 3: nonlocal attention, one thread per (b,g,n); 64-thread blocks,
// 512 blocks (2/CU). Wnq reads are wave-uniform -> scalar loads.
// ---------------------------------------------------------------------------
__global__ __launch_bounds__(64) void k_nonlocal(
    const float* __restrict__ abs_x, const float* __restrict__ Wnq,
    const float* __restrict__ kng, const float* __restrict__ vng,
    float* __restrict__ out)
{
    __shared__ float skn[CNG * K];
    __shared__ float svn[CNG * K];

    const int blk = blockIdx.x;          // 512 blocks: b(2b) g(2b) ntile(5b)
    const int b = blk >> 7;
    const int g = (blk >> 5) & 3;
    const int n = ((blk & 31) << 6) + threadIdx.x;
    const int bg = b * G + g;

    for (int i = threadIdx.x; i < CNG * K; i += 64) {
        skn[i] = kng[bg * CNG * K + i];
        svn[i] = vng[bg * CNG * K + i];
    }
    __syncthreads();

    float qn[CNG];
#pragma unroll
    for (int c = 0; c < CNG; c++) qn[c] = 0.f;
    const float* wqn = Wnq + (size_t)g * CNG * CH;
#pragma unroll 4
    for (int cc = 0; cc < CH; cc++) {
        const float ax = abs_x[((size_t)b * CH + cc) * N + n];
#pragma unroll
        for (int c = 0; c < CNG; c++)
            qn[c] = fmaf(wqn[c * CH + cc], ax, qn[c]);
    }

    float sc[K];
#pragma unroll
    for (int kk = 0; kk < K; kk++) {
        float v = 0.f;
#pragma unroll
        for (int c = 0; c < CNG; c++) v = fmaf(qn[c], skn[c * K + kk], v);
        sc[kk] = v;
    }
    float m = sc[0];
#pragma unroll
    for (int kk = 1; kk < K; kk++) m = fmaxf(m, sc[kk]);
    float sum = 0.f;
#pragma unroll
    for (int kk = 0; kk < K; kk++) { sc[kk] = expf(sc[kk] - m); sum += sc[kk]; }
    const float inv = 1.f / sum;
#pragma unroll
    for (int c = 0; c < CNG; c++) {
        float acc = 0.f;
#pragma unroll
        for (int kk = 0; kk < K; kk++)
            acc = fmaf(sc[kk] * inv, svn[c * K + kk], acc);
        out[((size_t)b * C + LCH + g * CNG + c) * N + n] = acc;
    }
}

// ---------------------------------------------------------------------------
extern "C" void kernel_launch(void* const* d_in, const int* in_sizes, int n_in,
                              void* d_out, int out_size, void* d_ws, size_t ws_size,
                              hipStream_t stream) {
    const float* x     = (const float*)d_in[0];
    const float* abs_x = (const float*)d_in[1];
    const int*   idx   = (const int*)d_in[2];
    const float* Wq    = (const float*)d_in[3];
    const float* Wk    = (const float*)d_in[4];
    const float* Wv    = (const float*)d_in[5];
    const float* Wnq   = (const float*)d_in[6];
    const float* Wnk   = (const float*)d_in[7];
    const float* Wnv   = (const float*)d_in[8];
    float* out = (float*)d_out;

    float* ws    = (float*)d_ws;
    float* score = ws;                          // B*G*N = 32768 floats
    float* kng   = ws + B * G * N;              // 2048 floats
    float* vng   = kng + B * G * CNG * K;       // 2048 floats

    hipMemsetAsync(score, 0, (size_t)B * G * N * sizeof(float), stream);

    k_local<<<B * (N / 4), 256, 0, stream>>>(x, idx, Wq, Wk, Wv, out, score);
    k_topk<<<B * G, 256, 0, stream>>>(abs_x, score, Wnk, Wnv, kng, vng);
    k_nonlocal<<<B * G * N / 64, 64, 0, stream>>>(abs_x, Wnq, kng, vng, out);
}

// Round 7
// 394.354 us; speedup vs baseline: 1.2447x; 1.2447x over previous
//
#include <hip/hip_runtime.h>
#include <math.h>

#define B   4
#define C   128
#define N   2048
#define K   16
#define G   4
#define LCH 96
#define NLCH 32
#define CLG 24   // LCH/G
#define CNG 8    // NLCH/G
#define CH  64   // C/2 (abs_x channels)

// ---------------------------------------------------------------------------
// Kernel 1: local path. One block = 4 consecutive n positions.
// Wave layout: lane = nsub(2b) x kk(4b). Wave g owns channel group g.
//   pass A: q,k projection (48 reg accumulators), float4 weight loads
//           -> score (in-lane) -> softmax over kk -> ow
//   scatter: atomicAdd ow into score[b,g,idx]  (argsort idx => collision-free
//            per (b,n), so scatter-add == reference .set + sum-over-n)
//   pass B: pool y[g][ns][c] = sum_kk ow*x  (16-lane shfl reduce), then
//           out_l = Wv . y  (projection AFTER kk-pooling — algebraically
//           identical, 16x fewer v-path FMAs, no accv registers)
// __launch_bounds__(256,4): cap VGPR at 128 so the 48 accs stay in registers
// (round-6 counters: VGPR=44 => accumulators were spilled; VALUBusy 51%).
// ---------------------------------------------------------------------------
__global__ __launch_bounds__(256, 4) void k_local(
    const float* __restrict__ x, const int* __restrict__ idx,
    const float* __restrict__ Wq, const float* __restrict__ Wk,
    const float* __restrict__ Wv,
    float* __restrict__ out, float* __restrict__ score)
{
    __shared__ float xs[C * 64];       // [c][nsub*16+kk]  32 KB
    __shared__ float yls[G][4][C];     // [g][ns][c] pooled x, 8 KB

    const int blk = blockIdx.x;          // b*(N/4) + n0/4
    const int b  = blk >> 9;
    const int n0 = (blk & 511) << 2;
    const int tid  = threadIdx.x;
    const int lane = tid & 63;
    const int g = __builtin_amdgcn_readfirstlane(tid >> 6);
    const int nsub = lane >> 4, kk = lane & 15;

    // ---- stage x[b,:,n0:n0+4,:] : 8192 floats = 2048 float4, coalesced ----
    {
        const float4* xg  = reinterpret_cast<const float4*>(x);
        float4*       xsv = reinterpret_cast<float4*>(xs);
        for (int i = tid; i < C * 16; i += 256) {
            const int c = i >> 4, j = i & 15;
            xsv[i] = xg[((size_t)(b * C + c) * N + n0) * 4 + j];
        }
    }
    __syncthreads();

    // ---- pass A: q,k projection; weights as float4 (1 load : 4 FMA) ----
    float accq[CLG], acck[CLG];
#pragma unroll
    for (int i = 0; i < CLG; i++) { accq[i] = 0.f; acck[i] = 0.f; }
    const float4* wq4 = reinterpret_cast<const float4*>(Wq + (size_t)g * CLG * C);
    const float4* wk4 = reinterpret_cast<const float4*>(Wk + (size_t)g * CLG * C);
    for (int c4 = 0; c4 < C / 4; c4++) {
        float xv0 = xs[(c4 * 4 + 0) * 64 + lane];
        float xv1 = xs[(c4 * 4 + 1) * 64 + lane];
        float xv2 = xs[(c4 * 4 + 2) * 64 + lane];
        float xv3 = xs[(c4 * 4 + 3) * 64 + lane];
#pragma unroll
        for (int i = 0; i < CLG; i++) {
            const float4 wqv = wq4[i * (C / 4) + c4];
            accq[i] = fmaf(wqv.x, xv0, accq[i]);
            accq[i] = fmaf(wqv.y, xv1, accq[i]);
            accq[i] = fmaf(wqv.z, xv2, accq[i]);
            accq[i] = fmaf(wqv.w, xv3, accq[i]);
            const float4 wkv = wk4[i * (C / 4) + c4];
            acck[i] = fmaf(wkv.x, xv0, acck[i]);
            acck[i] = fmaf(wkv.y, xv1, acck[i]);
            acck[i] = fmaf(wkv.z, xv2, acck[i]);
            acck[i] = fmaf(wkv.w, xv3, acck[i]);
        }
    }

    // ---- score (in-lane) + softmax over kk (16-lane groups) ----
    float s = 0.f;
#pragma unroll
    for (int i = 0; i < CLG; i++) s = fmaf(accq[i], acck[i], s);
    float m = s;
#pragma unroll
    for (int w = 1; w < 16; w <<= 1) m = fmaxf(m, __shfl_xor(m, w));
    const float e = expf(s - m);
    float sum = e;
#pragma unroll
    for (int w = 1; w < 16; w <<= 1) sum += __shfl_xor(sum, w);
    const float ow = e / sum;

    // ---- atomic scatter into score[b,g,idx] ----
    {
        const int m_idx = idx[((size_t)b * N + n0 + nsub) * K + kk];
        atomicAdd(&score[(b * G + g) * N + m_idx], ow);
    }

    // ---- pass B1: pool y[g][ns][c] = sum_kk ow * x[c][ns*16+kk] ----
    for (int c = 0; c < C; c++) {
        float t = ow * xs[c * 64 + lane];
        t += __shfl_xor(t, 1);
        t += __shfl_xor(t, 2);
        t += __shfl_xor(t, 4);
        t += __shfl_xor(t, 8);
        if (kk == 0) yls[g][nsub][c] = t;
    }
    __syncthreads();

    // ---- pass B2: out_l[b, g*24+o, n0..n0+3] = Wv[row] . y[g][ns][:] ----
    if (lane < CLG) {
        const int o = g * CLG + lane;
        const float4* wv4 = reinterpret_cast<const float4*>(Wv + (size_t)o * C);
        float a0 = 0.f, a1 = 0.f, a2 = 0.f, a3 = 0.f;
        for (int c4 = 0; c4 < C / 4; c4++) {
            const float4 wv = wv4[c4];
            const float4 y0 = *reinterpret_cast<const float4*>(&yls[g][0][c4 * 4]);
            const float4 y1 = *reinterpret_cast<const float4*>(&yls[g][1][c4 * 4]);
            const float4 y2 = *reinterpret_cast<const float4*>(&yls[g][2][c4 * 4]);
            const float4 y3 = *reinterpret_cast<const float4*>(&yls[g][3][c4 * 4]);
            a0 = fmaf(wv.x, y0.x, fmaf(wv.y, y0.y, fmaf(wv.z, y0.z, fmaf(wv.w, y0.w, a0))));
            a1 = fmaf(wv.x, y1.x, fmaf(wv.y, y1.y, fmaf(wv.z, y1.z, fmaf(wv.w, y1.w, a1))));
            a2 = fmaf(wv.x, y2.x, fmaf(wv.y, y2.y, fmaf(wv.z, y2.z, fmaf(wv.w, y2.w, a2))));
            a3 = fmaf(wv.x, y3.x, fmaf(wv.y, y3.y, fmaf(wv.z, y3.z, fmaf(wv.w, y3.w, a3))));
        }
        float4 r; r.x = a0; r.y = a1; r.z = a2; r.w = a3;
        *reinterpret_cast<float4*>(&out[((size_t)b * C + o) * N + n0]) = r;
    }
}

// ---------------------------------------------------------------------------
// Kernel 2: per (b,g) top-16 of score with lower-index tie-break (wave
// shfl reduction; tie-break = value desc, index asc at thread, lane and
// wave level -> matches jax.lax.top_k), then gather+project kn_g / vn_g,
// vn_g *= tanh(val).
// ---------------------------------------------------------------------------
__global__ __launch_bounds__(256) void k_topk(
    const float* __restrict__ abs_x, const float* __restrict__ score,
    const float* __restrict__ Wnk, const float* __restrict__ Wnv,
    float* __restrict__ kng, float* __restrict__ vng)
{
    __shared__ float s[N];
    __shared__ float rv[4];
    __shared__ int   ri[4];
    __shared__ int   selS[K];
    __shared__ float valS[K];

    const int bg = blockIdx.x;
    const int b = bg >> 2, g = bg & 3;
    const int tid = threadIdx.x;
    const int lane = tid & 63, w = tid >> 6;

    for (int i = tid; i < N; i += 256) s[i] = score[bg * N + i];
    __syncthreads();

    for (int t = 0; t < K; t++) {
        float bv = -INFINITY; int bi = N;
        for (int i = tid; i < N; i += 256) {
            const float v = s[i];
            if (v > bv) { bv = v; bi = i; }   // ascending stride: first-seen = lowest idx
        }
#pragma unroll
        for (int mask = 1; mask < 64; mask <<= 1) {
            const float ov = __shfl_xor(bv, mask);
            const int   oi = __shfl_xor(bi, mask);
            if (ov > bv || (ov == bv && oi < bi)) { bv = ov; bi = oi; }
        }
        if (lane == 0) { rv[w] = bv; ri[w] = bi; }
        __syncthreads();
        if (tid == 0) {
            float fv = rv[0]; int fi = ri[0];
            for (int j = 1; j < 4; j++)
                if (rv[j] > fv || (rv[j] == fv && ri[j] < fi)) { fv = rv[j]; fi = ri[j]; }
            selS[t] = fi; valS[t] = fv; s[fi] = -INFINITY;
        }
        __syncthreads();
    }

    // kn_g, vn_g: 8 channels x 16 selected positions, 64-length dots
    if (tid < CNG * K) {
        const int c = tid >> 4, kk = tid & 15;
        const int sel = selS[kk];
        const float* wkrow = Wnk + (g * CNG + c) * CH;
        const float* wvrow = Wnv + (g * CNG + c) * CH;
        float ka = 0.f, va = 0.f;
        for (int cc = 0; cc < CH; cc++) {
            const float ax = abs_x[((size_t)b * CH + cc) * N + sel];
            ka = fmaf(wkrow[cc], ax, ka);
            va = fmaf(wvrow[cc], ax, va);
        }
        va *= tanhf(valS[kk]);
        kng[bg * CNG * K + c * K + kk] = ka;
        vng[bg * CNG * K + c * K + kk] = va;
    }
}

// ---------------------------------------------------------------------------
// Kernel 3: nonlocal attention, one thread per (b,g,n); 64-thread blocks,
// 512 blocks. Wnq reads are wave-uniform -> scalar loads.
// ---------------------------------------------------------------------------
__global__ __launch_bounds__(64) void k_nonlocal(
    const float* __restrict__ abs_x, const float* __restrict__ Wnq,
    const float* __restrict__ kng, const float* __restrict__ vng,
    float* __restrict__ out)
{
    __shared__ float skn[CNG * K];
    __shared__ float svn[CNG * K];

    const int blk = blockIdx.x;          // 512 blocks: b(2b) g(2b) ntile(5b)
    const int b = blk >> 7;
    const int g = (blk >> 5) & 3;
    const int n = ((blk & 31) << 6) + threadIdx.x;
    const int bg = b * G + g;

    for (int i = threadIdx.x; i < CNG * K; i += 64) {
        skn[i] = kng[bg * CNG * K + i];
        svn[i] = vng[bg * CNG * K + i];
    }
    __syncthreads();

    float qn[CNG];
#pragma unroll
    for (int c = 0; c < CNG; c++) qn[c] = 0.f;
    const float* wqn = Wnq + (size_t)g * CNG * CH;
#pragma unroll 4
    for (int cc = 0; cc < CH; cc++) {
        const float ax = abs_x[((size_t)b * CH + cc) * N + n];
#pragma unroll
        for (int c = 0; c < CNG; c++)
            qn[c] = fmaf(wqn[c * CH + cc], ax, qn[c]);
    }

    float sc[K];
#pragma unroll
    for (int kk = 0; kk < K; kk++) {
        float v = 0.f;
#pragma unroll
        for (int c = 0; c < CNG; c++) v = fmaf(qn[c], skn[c * K + kk], v);
        sc[kk] = v;
    }
    float m = sc[0];
#pragma unroll
    for (int kk = 1; kk < K; kk++) m = fmaxf(m, sc[kk]);
    float sum = 0.f;
#pragma unroll
    for (int kk = 0; kk < K; kk++) { sc[kk] = expf(sc[kk] - m); sum += sc[kk]; }
    const float inv = 1.f / sum;
#pragma unroll
    for (int c = 0; c < CNG; c++) {
        float acc = 0.f;
#pragma unroll
        for (int kk = 0; kk < K; kk++)
            acc = fmaf(sc[kk] * inv, svn[c * K + kk], acc);
        out[((size_t)b * C + LCH + g * CNG + c) * N + n] = acc;
    }
}

// ---------------------------------------------------------------------------
extern "C" void kernel_launch(void* const* d_in, const int* in_sizes, int n_in,
                              void* d_out, int out_size, void* d_ws, size_t ws_size,
                              hipStream_t stream) {
    const float* x     = (const float*)d_in[0];
    const float* abs_x = (const float*)d_in[1];
    const int*   idx   = (const int*)d_in[2];
    const float* Wq    = (const float*)d_in[3];
    const float* Wk    = (const float*)d_in[4];
    const float* Wv    = (const float*)d_in[5];
    const float* Wnq   = (const float*)d_in[6];
    const float* Wnk   = (const float*)d_in[7];
    const float* Wnv   = (const float*)d_in[8];
    float* out = (float*)d_out;

    float* ws    = (float*)d_ws;
    float* score = ws;                          // B*G*N = 32768 floats
    float* kng   = ws + B * G * N;              // 2048 floats
    float* vng   = kng + B * G * CNG * K;       // 2048 floats

    hipMemsetAsync(score, 0, (size_t)B * G * N * sizeof(float), stream);

    k_local<<<B * (N / 4), 256, 0, stream>>>(x, idx, Wq, Wk, Wv, out, score);
    k_topk<<<B * G, 256, 0, stream>>>(abs_x, score, Wnk, Wnv, kng, vng);
    k_nonlocal<<<B * G * N / 64, 64, 0, stream>>>(abs_x, Wnq, kng, vng, out);
}

// Round 9
// 290.935 us; speedup vs baseline: 1.6871x; 1.3555x over previous
//
#include <hip/hip_runtime.h>
#include <math.h>

#define B   4
#define C   128
#define N   2048
#define K   16
#define G   4
#define LCH 96
#define NLCH 32
#define CLG 24   // LCH/G
#define CNG 8    // NLCH/G
#define CH  64   // C/2 (abs_x channels)
#define NT  16   // n-positions per k_local block
#define CPAD (C + 4)   // padded y row to avoid bank conflicts

// ---------------------------------------------------------------------------
// Kernel 1: local path. One block = 16 n positions, 512 threads = 8 waves.
// Wave wid = (g<<1)|h : group g, row-half h (12 q-rows + 12 k-rows).
// Lane = kk(4b)<<2 | m(2b); lane's 4 columns are n = n0 + m + 4j, j=0..3.
// V=4 columns per lane => 24 s_load_dwordx4 feed 768 FMA-cycles per c4
// (1 load / 32 cyc; R7's V=1 gave 1/8 cyc -> s_load latency-bound, VALU 22%).
// x streamed per-lane from global (no LDS staging); halves combine score
// partials via LDS; pooled y = sum_kk ow*x then out_l = Wv.y (algebraic
// identity, 16x fewer v-path FMAs).
// ---------------------------------------------------------------------------
__global__ __launch_bounds__(512, 3) void k_local(
    const float* __restrict__ x, const int* __restrict__ idx,
    const float* __restrict__ Wq, const float* __restrict__ Wk,
    const float* __restrict__ Wv,
    float* __restrict__ out, float* __restrict__ score)
{
    __shared__ float ps[G][2][NT][K];      // partial scores, 8 KB
    __shared__ float yls[G][NT][CPAD];     // pooled x, padded, 33 KB

    const int blk = blockIdx.x;            // b*(N/NT) + nt
    const int b  = blk >> 7;               // N/NT = 128
    const int n0 = (blk & 127) << 4;
    const int tid  = threadIdx.x;
    const int lane = tid & 63;
    const int wid = __builtin_amdgcn_readfirstlane(tid >> 6); // 0..7
    const int g = wid >> 1, h = wid & 1;
    const int kk = lane >> 2, m = lane & 3;

    // this wave's 12 q-rows / 12 k-rows
    const float4* wq4 = reinterpret_cast<const float4*>(Wq + (size_t)(g * CLG + h * 12) * C);
    const float4* wk4 = reinterpret_cast<const float4*>(Wk + (size_t)(g * CLG + h * 12) * C);

    // x base for this block: element (c, n0+m+4j, kk) at
    //   xb + c*N*K + m*K + kk + j*64
    const float* xb = x + ((size_t)b * C * N + (size_t)n0) * K + m * K + kk;

    float accq[12][4], acck[12][4];
#pragma unroll
    for (int i = 0; i < 12; i++)
#pragma unroll
        for (int j = 0; j < 4; j++) { accq[i][j] = 0.f; acck[i][j] = 0.f; }

    for (int c4 = 0; c4 < C / 4; c4++) {
        float xv[4][4];   // [cc][j]
#pragma unroll
        for (int cc = 0; cc < 4; cc++) {
            const float* p = xb + (size_t)(c4 * 4 + cc) * (N * K);
#pragma unroll
            for (int j = 0; j < 4; j++) xv[cc][j] = p[j * 64];
        }
#pragma unroll
        for (int i = 0; i < 12; i++) {
            const float4 aq = wq4[i * (C / 4) + c4];
            const float4 ak = wk4[i * (C / 4) + c4];
#pragma unroll
            for (int j = 0; j < 4; j++) {
                accq[i][j] = fmaf(aq.x, xv[0][j], accq[i][j]);
                accq[i][j] = fmaf(aq.y, xv[1][j], accq[i][j]);
                accq[i][j] = fmaf(aq.z, xv[2][j], accq[i][j]);
                accq[i][j] = fmaf(aq.w, xv[3][j], accq[i][j]);
                acck[i][j] = fmaf(ak.x, xv[0][j], acck[i][j]);
                acck[i][j] = fmaf(ak.y, xv[1][j], acck[i][j]);
                acck[i][j] = fmaf(ak.z, xv[2][j], acck[i][j]);
                acck[i][j] = fmaf(ak.w, xv[3][j], acck[i][j]);
            }
        }
    }

    // partial score over this wave's 12 channels
#pragma unroll
    for (int j = 0; j < 4; j++) {
        float s = 0.f;
#pragma unroll
        for (int i = 0; i < 12; i++) s = fmaf(accq[i][j], acck[i][j], s);
        ps[g][h][m + 4 * j][kk] = s;
    }
    __syncthreads();

    // combine halves + softmax over kk (lanes with same m: xor 4,8,16,32)
    float ow[4];
#pragma unroll
    for (int j = 0; j < 4; j++) {
        float s = ps[g][0][m + 4 * j][kk] + ps[g][1][m + 4 * j][kk];
        float mx = s;
        mx = fmaxf(mx, __shfl_xor(mx, 4));
        mx = fmaxf(mx, __shfl_xor(mx, 8));
        mx = fmaxf(mx, __shfl_xor(mx, 16));
        mx = fmaxf(mx, __shfl_xor(mx, 32));
        const float e = expf(s - mx);
        float sum = e;
        sum += __shfl_xor(sum, 4);
        sum += __shfl_xor(sum, 8);
        sum += __shfl_xor(sum, 16);
        sum += __shfl_xor(sum, 32);
        ow[j] = e / sum;
    }

    // atomic scatter (h==0 wave only; argsort idx => collision-free per (b,n),
    // so scatter-add == reference .set + sum-over-n)
    if (h == 0) {
#pragma unroll
        for (int j = 0; j < 4; j++) {
            const int mi = idx[((size_t)b * N + n0 + m + 4 * j) * K + kk];
            atomicAdd(&score[(b * G + g) * N + mi], ow[j]);
        }
    }

    // pool y[g][n][c] = sum_kk ow * x  (wave handles its c-half)
    for (int c = h * 64; c < h * 64 + 64; c++) {
        const float* p = xb + (size_t)c * (N * K);
        float t0 = ow[0] * p[0];
        float t1 = ow[1] * p[64];
        float t2 = ow[2] * p[128];
        float t3 = ow[3] * p[192];
        t0 += __shfl_xor(t0, 4); t0 += __shfl_xor(t0, 8); t0 += __shfl_xor(t0, 16); t0 += __shfl_xor(t0, 32);
        t1 += __shfl_xor(t1, 4); t1 += __shfl_xor(t1, 8); t1 += __shfl_xor(t1, 16); t1 += __shfl_xor(t1, 32);
        t2 += __shfl_xor(t2, 4); t2 += __shfl_xor(t2, 8); t2 += __shfl_xor(t2, 16); t2 += __shfl_xor(t2, 32);
        t3 += __shfl_xor(t3, 4); t3 += __shfl_xor(t3, 8); t3 += __shfl_xor(t3, 16); t3 += __shfl_xor(t3, 32);
        if (kk == 0) {
            yls[g][m + 0][c]  = t0;
            yls[g][m + 4][c]  = t1;
            yls[g][m + 8][c]  = t2;
            yls[g][m + 12][c] = t3;
        }
    }
    __syncthreads();

    // out_l[b, o, n0+n] = Wv[o] . y[o/24][n]  (1536 outputs, 3 per thread)
#pragma unroll
    for (int rep = 0; rep < 3; rep++) {
        const int o = rep * 32 + (tid >> 4);
        const int n = tid & 15;
        const float4* wv4 = reinterpret_cast<const float4*>(Wv + (size_t)o * C);
        const float* yr = &yls[o / CLG][n][0];
        float acc = 0.f;
        for (int c4 = 0; c4 < C / 4; c4++) {
            const float4 wv = wv4[c4];
            const float4 yv = *reinterpret_cast<const float4*>(&yr[c4 * 4]);
            acc = fmaf(wv.x, yv.x, fmaf(wv.y, yv.y, fmaf(wv.z, yv.z, fmaf(wv.w, yv.w, acc))));
        }
        out[((size_t)b * C + o) * N + n0 + n] = acc;
    }
}

// ---------------------------------------------------------------------------
// Kernel 2: per (b,g) top-16 of score with lower-index tie-break (value
// desc, index asc at thread/lane/wave level -> matches jax.lax.top_k),
// then gather the 16 selected abs_x columns into LDS (parallel, latency-
// hidden) and project kn_g / vn_g from LDS; vn_g *= tanh(val).
// ---------------------------------------------------------------------------
__global__ __launch_bounds__(256) void k_topk(
    const float* __restrict__ abs_x, const float* __restrict__ score,
    const float* __restrict__ Wnk, const float* __restrict__ Wnv,
    float* __restrict__ kng, float* __restrict__ vng)
{
    __shared__ float s[N];
    __shared__ float rv[4];
    __shared__ int   ri[4];
    __shared__ int   selS[K];
    __shared__ float valS[K];
    __shared__ float axs[CH][K];   // gathered abs_x columns, 4 KB

    const int bg = blockIdx.x;
    const int b = bg >> 2, g = bg & 3;
    const int tid = threadIdx.x;
    const int lane = tid & 63, w = tid >> 6;

    for (int i = tid; i < N; i += 256) s[i] = score[bg * N + i];
    __syncthreads();

    for (int t = 0; t < K; t++) {
        float bv = -INFINITY; int bi = N;
        for (int i = tid; i < N; i += 256) {
            const float v = s[i];
            if (v > bv) { bv = v; bi = i; }   // ascending stride: first-seen = lowest idx
        }
#pragma unroll
        for (int mask = 1; mask < 64; mask <<= 1) {
            const float ov = __shfl_xor(bv, mask);
            const int   oi = __shfl_xor(bi, mask);
            if (ov > bv || (ov == bv && oi < bi)) { bv = ov; bi = oi; }
        }
        if (lane == 0) { rv[w] = bv; ri[w] = bi; }
        __syncthreads();
        if (tid == 0) {
            float fv = rv[0]; int fi = ri[0];
            for (int j = 1; j < 4; j++)
                if (rv[j] > fv || (rv[j] == fv && ri[j] < fi)) { fv = rv[j]; fi = ri[j]; }
            selS[t] = fi; valS[t] = fv; s[fi] = -INFINITY;
        }
        __syncthreads();
    }

    // stage the 16 selected columns of abs_x: 1024 scattered loads, parallel
    for (int i = tid; i < CH * K; i += 256) {
        const int cc = i >> 4, kk = i & 15;
        axs[cc][kk] = abs_x[((size_t)b * CH + cc) * N + selS[kk]];
    }
    __syncthreads();

    // kn, vn: thread = (c 8) x (kk 16) x (cc-half 2), dot-32 each, pair-combine
    {
        const int c = tid >> 5, kk = (tid >> 1) & 15, hh = tid & 1;
        const float* wkr = Wnk + ((size_t)g * CNG + c) * CH + hh * 32;
        const float* wvr = Wnv + ((size_t)g * CNG + c) * CH + hh * 32;
        float ka = 0.f, va = 0.f;
#pragma unroll 8
        for (int cc = 0; cc < 32; cc++) {
            const float ax = axs[hh * 32 + cc][kk];
            ka = fmaf(wkr[cc], ax, ka);
            va = fmaf(wvr[cc], ax, va);
        }
        ka += __shfl_xor(ka, 1);
        va += __shfl_xor(va, 1);
        if (hh == 0) {
            va *= tanhf(valS[kk]);
            kng[bg * CNG * K + c * K + kk] = ka;
            vng[bg * CNG * K + c * K + kk] = va;
        }
    }
}

// ---------------------------------------------------------------------------
// Kernel 3: nonlocal attention, one thread per (b,g,n); 64-thread blocks,
// 512 blocks. Wnq reads are wave-uniform -> scalar loads.
// ---------------------------------------------------------------------------
__global__ __launch_bounds__(64) void k_nonlocal(
    const float* __restrict__ abs_x, const float* __restrict__ Wnq,
    const float* __restrict__ kng, const float* __restrict__ vng,
    float* __restrict__ out)
{
    __shared__ float skn[CNG * K];
    __shared__ float svn[CNG * K];

    const int blk = blockIdx.x;          // 512 blocks: b(2b) g(2b) ntile(5b)
    const int b = blk >> 7;
    const int g = (blk >> 5) & 3;
    const int n = ((blk & 31) << 6) + threadIdx.x;
    const int bg = b * G + g;

    for (int i = threadIdx.x; i < CNG * K; i += 64) {
        skn[i] = kng[bg * CNG * K + i];
        svn[i] = vng[bg * CNG * K + i];
    }
    __syncthreads();

    float qn[CNG];
#pragma unroll
    for (int c = 0; c < CNG; c++) qn[c] = 0.f;
    const float* wqn = Wnq + (size_t)g * CNG * CH;
#pragma unroll 4
    for (int cc = 0; cc < CH; cc++) {
        const float ax = abs_x[((size_t)b * CH + cc) * N + n];
#pragma unroll
        for (int c = 0; c < CNG; c++)
            qn[c] = fmaf(wqn[c * CH + cc], ax, qn[c]);
    }

    float sc[K];
#pragma unroll
    for (int kk = 0; kk < K; kk++) {
        float v = 0.f;
#pragma unroll
        for (int c = 0; c < CNG; c++) v = fmaf(qn[c], skn[c * K + kk], v);
        sc[kk] = v;
    }
    float m = sc[0];
#pragma unroll
    for (int kk = 1; kk < K; kk++) m = fmaxf(m, sc[kk]);
    float sum = 0.f;
#pragma unroll
    for (int kk = 0; kk < K; kk++) { sc[kk] = expf(sc[kk] - m); sum += sc[kk]; }
    const float inv = 1.f / sum;
#pragma unroll
    for (int c = 0; c < CNG; c++) {
        float acc = 0.f;
#pragma unroll
        for (int kk = 0; kk < K; kk++)
            acc = fmaf(sc[kk] * inv, svn[c * K + kk], acc);
        out[((size_t)b * C + LCH + g * CNG + c) * N + n] = acc;
    }
}

// ---------------------------------------------------------------------------
extern "C" void kernel_launch(void* const* d_in, const int* in_sizes, int n_in,
                              void* d_out, int out_size, void* d_ws, size_t ws_size,
                              hipStream_t stream) {
    const float* x     = (const float*)d_in[0];
    const float* abs_x = (const float*)d_in[1];
    const int*   idx   = (const int*)d_in[2];
    const float* Wq    = (const float*)d_in[3];
    const float* Wk    = (const float*)d_in[4];
    const float* Wv    = (const float*)d_in[5];
    const float* Wnq   = (const float*)d_in[6];
    const float* Wnk   = (const float*)d_in[7];
    const float* Wnv   = (const float*)d_in[8];
    float* out = (float*)d_out;

    float* ws    = (float*)d_ws;
    float* score = ws;                          // B*G*N = 32768 floats
    float* kng   = ws + B * G * N;              // 2048 floats
    float* vng   = kng + B * G * CNG * K;       // 2048 floats

    hipMemsetAsync(score, 0, (size_t)B * G * N * sizeof(float), stream);

    k_local<<<B * (N / NT), 512, 0, stream>>>(x, idx, Wq, Wk, Wv, out, score);
    k_topk<<<B * G, 256, 0, stream>>>(abs_x, score, Wnk, Wnv, kng, vng);
    k_nonlocal<<<B * G * N / 64, 64, 0, stream>>>(abs_x, Wnq, kng, vng, out);
}

// Round 11
// 264.833 us; speedup vs baseline: 1.8534x; 1.0986x over previous
//
#include <hip/hip_runtime.h>
#include <math.h>

#define B   4
#define C   128
#define N   2048
#define K   16
#define G   4
#define LCH 96
#define NLCH 32
#define CLG 24   // LCH/G
#define CNG 8    // NLCH/G
#define CH  64   // C/2 (abs_x channels)
#define NT  8    // n-positions per k_local block
#define CPAD (C + 4)   // padded y row to avoid bank conflicts

// ---------------------------------------------------------------------------
// Kernel 1: local path. One block = 8 n positions, 512 threads = 8 waves,
// grid 1024 blocks (4/CU static). Wave wid = (g<<1)|h : group g, row-half h
// (12 q-rows + 12 k-rows). Lane = kk(4b)<<2 | m(2b); lane's 2 columns are
// n = n0 + m + 4j, j=0..1.
// Register budget deliberately ~80 (48 accs + 2x8 xv dbuf): R9 showed the
// allocator caps ~72 VGPR and defeats 96-acc blocking (fission/spill ->
// VALU 35%, occ 23%). x prefetched via register double-buffer; weights are
// wave-uniform float4 s_loads (24 per 384 FMA-cycles).
// Pooled y = sum_kk ow*x then out_l = Wv.y (algebraic identity, 16x fewer
// v-path FMAs).
// ---------------------------------------------------------------------------
__global__ __launch_bounds__(512, 2) void k_local(
    const float* __restrict__ x, const int* __restrict__ idx,
    const float* __restrict__ Wq, const float* __restrict__ Wk,
    const float* __restrict__ Wv,
    float* __restrict__ out, float* __restrict__ score)
{
    __shared__ float ps[G][2][NT][K];      // partial scores, 4 KB
    __shared__ float yls[G][NT][CPAD];     // pooled x, padded, 16.9 KB

    const int blk = blockIdx.x;            // b*(N/NT) + nt
    const int b  = blk >> 8;               // N/NT = 256
    const int n0 = (blk & 255) << 3;
    const int tid  = threadIdx.x;
    const int lane = tid & 63;
    const int wid = __builtin_amdgcn_readfirstlane(tid >> 6); // 0..7
    const int g = wid >> 1, h = wid & 1;
    const int kk = lane >> 2, m = lane & 3;

    // this wave's 12 q-rows / 12 k-rows
    const float4* wq4 = reinterpret_cast<const float4*>(Wq + (size_t)(g * CLG + h * 12) * C);
    const float4* wk4 = reinterpret_cast<const float4*>(Wk + (size_t)(g * CLG + h * 12) * C);

    // x base: element (c, n0+m+4j, kk) at xb + c*N*K + j*64
    const float* xb = x + ((size_t)b * C * N + (size_t)n0) * K + m * K + kk;

    float accq[12][2], acck[12][2];
#pragma unroll
    for (int i = 0; i < 12; i++)
#pragma unroll
        for (int j = 0; j < 2; j++) { accq[i][j] = 0.f; acck[i][j] = 0.f; }

    // register double-buffer for x
    float cur[4][2], nxt[4][2];
#pragma unroll
    for (int cc = 0; cc < 4; cc++)
#pragma unroll
        for (int j = 0; j < 2; j++)
            cur[cc][j] = xb[(size_t)cc * (N * K) + j * 64];

    for (int c4 = 0; c4 < C / 4; c4++) {
        if (c4 < C / 4 - 1) {
#pragma unroll
            for (int cc = 0; cc < 4; cc++)
#pragma unroll
                for (int j = 0; j < 2; j++)
                    nxt[cc][j] = xb[(size_t)((c4 + 1) * 4 + cc) * (N * K) + j * 64];
        }
#pragma unroll
        for (int i = 0; i < 12; i++) {
            const float4 aq = wq4[i * (C / 4) + c4];
            const float4 ak = wk4[i * (C / 4) + c4];
#pragma unroll
            for (int j = 0; j < 2; j++) {
                accq[i][j] = fmaf(aq.x, cur[0][j], accq[i][j]);
                accq[i][j] = fmaf(aq.y, cur[1][j], accq[i][j]);
                accq[i][j] = fmaf(aq.z, cur[2][j], accq[i][j]);
                accq[i][j] = fmaf(aq.w, cur[3][j], accq[i][j]);
                acck[i][j] = fmaf(ak.x, cur[0][j], acck[i][j]);
                acck[i][j] = fmaf(ak.y, cur[1][j], acck[i][j]);
                acck[i][j] = fmaf(ak.z, cur[2][j], acck[i][j]);
                acck[i][j] = fmaf(ak.w, cur[3][j], acck[i][j]);
            }
        }
#pragma unroll
        for (int cc = 0; cc < 4; cc++)
#pragma unroll
            for (int j = 0; j < 2; j++)
                cur[cc][j] = nxt[cc][j];
    }

    // partial score over this wave's 12 channels
#pragma unroll
    for (int j = 0; j < 2; j++) {
        float s = 0.f;
#pragma unroll
        for (int i = 0; i < 12; i++) s = fmaf(accq[i][j], acck[i][j], s);
        ps[g][h][m + 4 * j][kk] = s;
    }
    __syncthreads();

    // combine halves + softmax over kk (xor 4,8,16,32 flips only kk bits)
    float ow[2];
#pragma unroll
    for (int j = 0; j < 2; j++) {
        float s = ps[g][0][m + 4 * j][kk] + ps[g][1][m + 4 * j][kk];
        float mx = s;
        mx = fmaxf(mx, __shfl_xor(mx, 4));
        mx = fmaxf(mx, __shfl_xor(mx, 8));
        mx = fmaxf(mx, __shfl_xor(mx, 16));
        mx = fmaxf(mx, __shfl_xor(mx, 32));
        const float e = expf(s - mx);
        float sum = e;
        sum += __shfl_xor(sum, 4);
        sum += __shfl_xor(sum, 8);
        sum += __shfl_xor(sum, 16);
        sum += __shfl_xor(sum, 32);
        ow[j] = e / sum;
    }

    // atomic scatter (h==0 waves only; argsort idx => collision-free per
    // (b,n), so scatter-add == reference .set + sum-over-n)
    if (h == 0) {
#pragma unroll
        for (int j = 0; j < 2; j++) {
            const int mi = idx[((size_t)b * N + n0 + m + 4 * j) * K + kk];
            atomicAdd(&score[(b * G + g) * N + mi], ow[j]);
        }
    }

    // pool y[g][n][c] = sum_kk ow * x  (wave handles its c-half; reads L2-hot)
    for (int c = h * 64; c < h * 64 + 64; c++) {
        const float* p = xb + (size_t)c * (N * K);
        float t0 = ow[0] * p[0];
        float t1 = ow[1] * p[64];
        t0 += __shfl_xor(t0, 4); t0 += __shfl_xor(t0, 8); t0 += __shfl_xor(t0, 16); t0 += __shfl_xor(t0, 32);
        t1 += __shfl_xor(t1, 4); t1 += __shfl_xor(t1, 8); t1 += __shfl_xor(t1, 16); t1 += __shfl_xor(t1, 32);
        if (kk == 0) {
            yls[g][m][c]     = t0;
            yls[g][m + 4][c] = t1;
        }
    }
    __syncthreads();

    // out_l[b, o, n0+n] = Wv[o] . y[o/24][n]  (768 outputs)
#pragma unroll
    for (int rep = 0; rep < 2; rep++) {
        const int o = rep * 64 + (tid >> 3);
        const int n = tid & 7;
        if (o < LCH) {
            const float4* wv4 = reinterpret_cast<const float4*>(Wv + (size_t)o * C);
            const float* yr = &yls[o / CLG][n][0];
            float acc = 0.f;
            for (int c4 = 0; c4 < C / 4; c4++) {
                const float4 wv = wv4[c4];
                const float4 yv = *reinterpret_cast<const float4*>(&yr[c4 * 4]);
                acc = fmaf(wv.x, yv.x, fmaf(wv.y, yv.y, fmaf(wv.z, yv.z, fmaf(wv.w, yv.w, acc))));
            }
            out[((size_t)b * C + o) * N + n0 + n] = acc;
        }
    }
}

// ---------------------------------------------------------------------------
// Kernel 2: per (b,g) top-16 of score with lower-index tie-break (value
// desc, index asc at thread/lane/wave level -> matches jax.lax.top_k),
// then gather the 16 selected abs_x columns into LDS and project
// kn_g / vn_g from LDS; vn_g *= tanh(val).
// ---------------------------------------------------------------------------
__global__ __launch_bounds__(256) void k_topk(
    const float* __restrict__ abs_x, const float* __restrict__ score,
    const float* __restrict__ Wnk, const float* __restrict__ Wnv,
    float* __restrict__ kng, float* __restrict__ vng)
{
    __shared__ float s[N];
    __shared__ float rv[4];
    __shared__ int   ri[4];
    __shared__ int   selS[K];
    __shared__ float valS[K];
    __shared__ float axs[CH][K];   // gathered abs_x columns, 4 KB

    const int bg = blockIdx.x;
    const int b = bg >> 2, g = bg & 3;
    const int tid = threadIdx.x;
    const int lane = tid & 63, w = tid >> 6;

    for (int i = tid; i < N; i += 256) s[i] = score[bg * N + i];
    __syncthreads();

    for (int t = 0; t < K; t++) {
        float bv = -INFINITY; int bi = N;
        for (int i = tid; i < N; i += 256) {
            const float v = s[i];
            if (v > bv) { bv = v; bi = i; }   // ascending stride: first-seen = lowest idx
        }
#pragma unroll
        for (int mask = 1; mask < 64; mask <<= 1) {
            const float ov = __shfl_xor(bv, mask);
            const int   oi = __shfl_xor(bi, mask);
            if (ov > bv || (ov == bv && oi < bi)) { bv = ov; bi = oi; }
        }
        if (lane == 0) { rv[w] = bv; ri[w] = bi; }
        __syncthreads();
        if (tid == 0) {
            float fv = rv[0]; int fi = ri[0];
            for (int j = 1; j < 4; j++)
                if (rv[j] > fv || (rv[j] == fv && ri[j] < fi)) { fv = rv[j]; fi = ri[j]; }
            selS[t] = fi; valS[t] = fv; s[fi] = -INFINITY;
        }
        __syncthreads();
    }

    // stage the 16 selected columns of abs_x: 1024 scattered loads, parallel
    for (int i = tid; i < CH * K; i += 256) {
        const int cc = i >> 4, kk = i & 15;
        axs[cc][kk] = abs_x[((size_t)b * CH + cc) * N + selS[kk]];
    }
    __syncthreads();

    // kn, vn: thread = (c 8) x (kk 16) x (cc-half 2), dot-32 each, pair-combine
    {
        const int c = tid >> 5, kk = (tid >> 1) & 15, hh = tid & 1;
        const float* wkr = Wnk + ((size_t)g * CNG + c) * CH + hh * 32;
        const float* wvr = Wnv + ((size_t)g * CNG + c) * CH + hh * 32;
        float ka = 0.f, va = 0.f;
#pragma unroll 8
        for (int cc = 0; cc < 32; cc++) {
            const float ax = axs[hh * 32 + cc][kk];
            ka = fmaf(wkr[cc], ax, ka);
            va = fmaf(wvr[cc], ax, va);
        }
        ka += __shfl_xor(ka, 1);
        va += __shfl_xor(va, 1);
        if (hh == 0) {
            va *= tanhf(valS[kk]);
            kng[bg * CNG * K + c * K + kk] = ka;
            vng[bg * CNG * K + c * K + kk] = va;
        }
    }
}

// ---------------------------------------------------------------------------
// Kernel 3: nonlocal attention, one thread per (b,g,n); 64-thread blocks,
// 512 blocks. Wnq reads are wave-uniform -> scalar loads.
// ---------------------------------------------------------------------------
__global__ __launch_bounds__(64) void k_nonlocal(
    const float* __restrict__ abs_x, const float* __restrict__ Wnq,
    const float* __restrict__ kng, const float* __restrict__ vng,
    float* __restrict__ out)
{
    __shared__ float skn[CNG * K];
    __shared__ float svn[CNG * K];

    const int blk = blockIdx.x;          // 512 blocks: b(2b) g(2b) ntile(5b)
    const int b = blk >> 7;
    const int g = (blk >> 5) & 3;
    const int n = ((blk & 31) << 6) + threadIdx.x;
    const int bg = b * G + g;

    for (int i = threadIdx.x; i < CNG * K; i += 64) {
        skn[i] = kng[bg * CNG * K + i];
        svn[i] = vng[bg * CNG * K + i];
    }
    __syncthreads();

    float qn[CNG];
#pragma unroll
    for (int c = 0; c < CNG; c++) qn[c] = 0.f;
    const float* wqn = Wnq + (size_t)g * CNG * CH;
#pragma unroll 4
    for (int cc = 0; cc < CH; cc++) {
        const float ax = abs_x[((size_t)b * CH + cc) * N + n];
#pragma unroll
        for (int c = 0; c < CNG; c++)
            qn[c] = fmaf(wqn[c * CH + cc], ax, qn[c]);
    }

    float sc[K];
#pragma unroll
    for (int kk = 0; kk < K; kk++) {
        float v = 0.f;
#pragma unroll
        for (int c = 0; c < CNG; c++) v = fmaf(qn[c], skn[c * K + kk], v);
        sc[kk] = v;
    }
    float m = sc[0];
#pragma unroll
    for (int kk = 1; kk < K; kk++) m = fmaxf(m, sc[kk]);
    float sum = 0.f;
#pragma unroll
    for (int kk = 0; kk < K; kk++) { sc[kk] = expf(sc[kk] - m); sum += sc[kk]; }
    const float inv = 1.f / sum;
#pragma unroll
    for (int c = 0; c < CNG; c++) {
        float acc = 0.f;
#pragma unroll
        for (int kk = 0; kk < K; kk++)
            acc = fmaf(sc[kk] * inv, svn[c * K + kk], acc);
        out[((size_t)b * C + LCH + g * CNG + c) * N + n] = acc;
    }
}

// ---------------------------------------------------------------------------
extern "C" void kernel_launch(void* const* d_in, const int* in_sizes, int n_in,
                              void* d_out, int out_size, void* d_ws, size_t ws_size,
                              hipStream_t stream) {
    const float* x     = (const float*)d_in[0];
    const float* abs_x = (const float*)d_in[1];
    const int*   idx   = (const int*)d_in[2];
    const float* Wq    = (const float*)d_in[3];
    const float* Wk    = (const float*)d_in[4];
    const float* Wv    = (const float*)d_in[5];
    const float* Wnq   = (const float*)d_in[6];
    const float* Wnk   = (const float*)d_in[7];
    const float* Wnv   = (const float*)d_in[8];
    float* out = (float*)d_out;

    float* ws    = (float*)d_ws;
    float* score = ws;                          // B*G*N = 32768 floats
    float* kng   = ws + B * G * N;              // 2048 floats
    float* vng   = kng + B * G * CNG * K;       // 2048 floats

    hipMemsetAsync(score, 0, (size_t)B * G * N * sizeof(float), stream);

    k_local<<<B * (N / NT), 512, 0, stream>>>(x, idx, Wq, Wk, Wv, out, score);
    k_topk<<<B * G, 256, 0, stream>>>(abs_x, score, Wnk, Wnv, kng, vng);
    k_nonlocal<<<B * G * N / 64, 64, 0, stream>>>(abs_x, Wnq, kng, vng, out);
}